// Round 16
// baseline (543.533 us; speedup 1.0000x reference)
//
#include <hip/hip_runtime.h>

#define NN    100000   // nodes
#define NEDGE 100000   // edges per relation
#define NRELS 6
#define HIDD  256
#define NGR   128      // graphs
#define NKEY  (NRELS * NN)        // 600000 (rel,tgt) keys
#define NEDGT (NRELS * NEDGE)     // 600000 edges total
#define WFRAG_ELEMS (4 * 7 * 16 * 2 * 64 * 8)   // 458752 bf16 per layer
#define SMASK 0xFFFFF             // src field of epack (src < 2^17)
#define NSHARD 8                  // pooled shards (atomic de-contention)

typedef __bf16 bf16;
typedef __bf16 bf16x4 __attribute__((ext_vector_type(4)));
typedef __bf16 bf16x8 __attribute__((ext_vector_type(8)));
typedef float  f32x4  __attribute__((ext_vector_type(4)));
typedef float  f32x16 __attribute__((ext_vector_type(16)));

__device__ __forceinline__ float readlane_f(float v, int sl) {
    return __int_as_float(__builtin_amdgcn_readlane(__float_as_int(v), sl));
}

// ================= CSR build (key = rel*NN + tgt) =================
__global__ __launch_bounds__(256)
void hist_kernel(const int* __restrict__ edges, int* __restrict__ hist)
{
    int i = blockIdx.x * 256 + threadIdx.x;
    if (i >= NEDGT) return;
    int r = i / NEDGE;
    int e = i - r * NEDGE;
    int t = edges[r * (2 * NEDGE) + NEDGE + e];
    atomicAdd(&hist[r * NN + t], 1);
}

__global__ __launch_bounds__(256)
void scan_l0(const int* __restrict__ in, int* __restrict__ out, int* __restrict__ bsum, int n)
{
    __shared__ int sdata[256];
    const int t = threadIdx.x;
    const int base = blockIdx.x * 2048 + t * 8;
    int v[8]; int s = 0;
#pragma unroll
    for (int i = 0; i < 8; ++i) {
        int idx = base + i;
        int x = (idx < n) ? in[idx] : 0;
        v[i] = s; s += x;
    }
    sdata[t] = s;
    __syncthreads();
    for (int off = 1; off < 256; off <<= 1) {
        int y = (t >= off) ? sdata[t - off] : 0;
        __syncthreads();
        sdata[t] += y;
        __syncthreads();
    }
    int excl = sdata[t] - s;
#pragma unroll
    for (int i = 0; i < 8; ++i) {
        int idx = base + i;
        if (idx < n) out[idx] = excl + v[i];
    }
    if (t == 0) bsum[blockIdx.x] = sdata[255];
}

__global__ __launch_bounds__(256)
void scan_l1(int* __restrict__ bsum, int n)
{
    __shared__ int sdata[256];
    const int t = threadIdx.x;
    const int base = t * 8;
    int v[8]; int s = 0;
#pragma unroll
    for (int i = 0; i < 8; ++i) {
        int idx = base + i;
        int x = (idx < n) ? bsum[idx] : 0;
        v[i] = s; s += x;
    }
    sdata[t] = s;
    __syncthreads();
    for (int off = 1; off < 256; off <<= 1) {
        int y = (t >= off) ? sdata[t - off] : 0;
        __syncthreads();
        sdata[t] += y;
        __syncthreads();
    }
    int excl = sdata[t] - s;
#pragma unroll
    for (int i = 0; i < 8; ++i) {
        int idx = base + i;
        if (idx < n) bsum[idx] = excl + v[i];
    }
}

// add block sums; cursor copy; sentinel; fused invdeg; fused graph-size counts
__global__ __launch_bounds__(256)
void scan_l2(int* __restrict__ offs, int* __restrict__ cursor, const int* __restrict__ bsum,
             const int* __restrict__ hist, float* __restrict__ invdeg,
             const int* __restrict__ batch_ids, float* __restrict__ cnt, int n)
{
    int idx = blockIdx.x * 256 + threadIdx.x;
    if (idx == 0) offs[NKEY] = NEDGT;

    // graph-size counts (runs within each wave; batch_ids sorted)
    {
        const int lane = threadIdx.x & 63;
        const bool valid = idx < NN;
        const int gv = valid ? batch_ids[idx] : -1;
        const int gprev = __shfl(gv, lane - 1);
        const bool head = valid && (lane == 0 || gv != gprev);
        const bool stop = head || !valid;
        const unsigned long long mask = __ballot(stop);
        if (head) {
            unsigned long long above = (lane == 63) ? 0ull : (mask >> (lane + 1));
            const int next = above ? (lane + 1 + __builtin_ctzll(above)) : 64;
            atomicAdd(&cnt[gv], (float)(next - lane));
        }
    }

    if (idx < NN) {
        int d = 0;
#pragma unroll
        for (int r = 0; r < NRELS; ++r) d += hist[r * NN + idx];
        invdeg[idx] = 1.0f / fmaxf((float)d, 1.0f);
    }
    if (idx >= n) return;
    int v = offs[idx] + bsum[idx >> 11];
    offs[idx] = v;
    cursor[idx] = v;
}

// epack = src | ((tgt & 15) << 20); epack2 = xt[src]*256 + xs[src] (etab row)
__global__ __launch_bounds__(256)
void scatter_kernel(const int* __restrict__ edges, int* __restrict__ cursor,
                    const int* __restrict__ xt, const int* __restrict__ xs,
                    int* __restrict__ epack, int* __restrict__ epack2)
{
    int i = blockIdx.x * 256 + threadIdx.x;
    if (i >= NEDGT) return;
    int r = i / NEDGE;
    int e = i - r * NEDGE;
    int s = edges[r * (2 * NEDGE) + e];
    int t = edges[r * (2 * NEDGE) + NEDGE + e];
    int pos = atomicAdd(&cursor[r * NN + t], 1);
    epack[pos] = s | ((t & 15) << 20);
    epack2[pos] = xt[s] * 256 + xs[s];
}

// ---------------- etab[c][f]: concat embedding for combo c = xt*256+xs (bf16) ----------------
__global__ __launch_bounds__(256)
void build_etab(const float* __restrict__ temb, const float* __restrict__ semb,
                bf16* __restrict__ etab)
{
    const int c = blockIdx.x;          // 0..1023
    const int f = threadIdx.x;         // 0..255
    const int t = c >> 8, s = c & 255;
    float v = (f < 128) ? temb[t * 128 + f] : semb[s * 128 + (f - 128)];
    etab[c * 256 + f] = (bf16)v;
}

// ---------------- Wfrag: B pre-swizzled into MFMA fragment order ----------------
__global__ __launch_bounds__(256)
void build_wfrag(const float* __restrict__ Wr0, const float* __restrict__ Ws0,
                 const float* __restrict__ Wr1, const float* __restrict__ Ws1,
                 bf16* __restrict__ Wf0, bf16* __restrict__ Wf1)
{
    const int seg = blockIdx.x;     // 0..6
    const int step = blockIdx.y;    // 0..15
    const int layer = blockIdx.z;   // 0..1
    const int tid = threadIdx.x;
    const int w = tid >> 6;
    const int lane = tid & 63;
    const int l31 = lane & 31;
    const int lhi = lane >> 5;

    const float* Wr = layer ? Wr1 : Wr0;
    const float* Ws = layer ? Ws1 : Ws0;
    const float* src = (seg < 6) ? (Wr + ((size_t)seg << 16)) : Ws;
    bf16* Wf = layer ? Wf1 : Wf0;

    const int kb = step * 16 + lhi * 8;   // segment-local k
#pragma unroll
    for (int ct = 0; ct < 2; ++ct) {
        const int n = w * 64 + ct * 32 + l31;
        bf16x8 o;
#pragma unroll
        for (int j = 0; j < 8; ++j)
            o[j] = (bf16)src[(size_t)(kb + j) * 256 + n];
        const size_t fb_idx = (size_t)(((w * 7 + seg) * 16 + step) * 2 + ct) * 64 + lane;
        *(bf16x8*)(Wf + fb_idx * 8) = o;
    }
}

// ---------------- fused RGCN layer ----------------
// R12 gather structure (occupancy knee: arch 84 + acc 64 = 148 regs at (256,3)).
// Unified single-level gather: row source = hin (L0: etab, 512KB L2-hot, rows via
// epack2; L1: h1, rows via epack&SMASK). Unconditional clamped DEPTH=16 bursts.
// POOL epilogue (L1): mean-pool fused, atomics into XCD-sharded pooled copies
// (blockIdx&7) to kill same-address cross-XCD serialization (R15: 301us, occ 7%).
template<bool L0, bool POOL>
__global__ __launch_bounds__(256, 3)
void rgcn_fused(const bf16* __restrict__ hin,
                const int* __restrict__ xt, const int* __restrict__ xs,
                const float* __restrict__ temb, const float* __restrict__ semb,
                const bf16* __restrict__ Wfrag, const float* __restrict__ bias,
                const float* __restrict__ invdeg, const int* __restrict__ offs,
                const int* __restrict__ epack, const int* __restrict__ epack2,
                const int* __restrict__ batch_ids,
                float* __restrict__ pooled, bf16* __restrict__ hout)
{
    constexpr int DEPTH = 16;
    const int m0 = blockIdx.x * 64;
    const int tid = threadIdx.x;
    const int lane = tid & 63;
    const int w = tid >> 6;
    const int l31 = lane & 31;
    const int lhi = lane >> 5;
    const int rbase = w * 16;                 // this wave's first tile-local row

    __shared__ __align__(16) bf16 As[64 * HIDD];   // 32 KB

    f32x16 acc[2][2] = {};

    // lane i (i&15) holds invdeg of tile-local row rbase + (i&15); readlane at flush
    int ivrow = m0 + rbase + (lane & 15);
    if (ivrow >= NN) ivrow = NN - 1;
    const float ivreg = invdeg[ivrow];

    for (int seg = 0; seg < 7; ++seg) {
        __syncthreads();   // previous seg's MFMA reads of As complete

        // ---- zero this wave's 16 rows ----
#pragma unroll
        for (int z = 0; z < 8; ++z) {
            const int row = rbase + lhi * 8 + z;
            const int unit = row * 32 + (l31 ^ (row & 7));
            *(bf16x8*)&As[unit * 8] = (bf16x8)(bf16)0.0f;
        }

        if (seg == 6) {
            // ---- self segment: copy h rows / inline embed ----
#pragma unroll
            for (int z = 0; z < 8; ++z) {
                const int row = rbase + lhi * 8 + z;
                const int gr = m0 + row;
                if (gr < NN) {
                    bf16x8 o;
                    if (L0) {
                        const int f0 = l31 * 8;
                        const float* src = (f0 < 128) ? (temb + xt[gr] * 128 + f0)
                                                      : (semb + xs[gr] * 128 + (f0 - 128));
                        f32x4 x0 = *(const f32x4*)src;
                        f32x4 x1 = *(const f32x4*)(src + 4);
                        o[0] = (bf16)x0[0]; o[1] = (bf16)x0[1];
                        o[2] = (bf16)x0[2]; o[3] = (bf16)x0[3];
                        o[4] = (bf16)x1[0]; o[5] = (bf16)x1[1];
                        o[6] = (bf16)x1[2]; o[7] = (bf16)x1[3];
                    } else {
                        o = *(const bf16x8*)(hin + ((size_t)gr << 8) + l31 * 8);
                    }
                    const int unit = row * 32 + (l31 ^ (row & 7));
                    *(bf16x8*)&As[unit * 8] = o;
                }
            }
        } else {
            // ---- aggregation for rows [m0+rbase, +16) ----
            const int gr0 = m0 + rbase;
            if (gr0 < NN) {
                const int rend = (gr0 + 16 < NN) ? (gr0 + 16) : NN;
                int st = offs[seg * NN + gr0];
                const int en = offs[seg * NN + rend];

                float a0 = 0.f, a1 = 0.f, a2 = 0.f, a3 = 0.f;
                int cur = -1;   // wave-uniform tile-local row (0..15)

                while (st < en) {
                    const int cnt = (en - st < 64) ? (en - st) : 64;
                    const int idx = st + ((lane < cnt) ? lane : (cnt - 1));
                    const int pv = epack[idx];                 // tgt meta (clamped)
                    const int rv = L0 ? epack2[idx]            // etab row
                                      : (pv & SMASK);          // h row

                    for (int base = 0; base < cnt; base += DEPTH) {
                        // ---- unconditional burst of DEPTH gathers (clamped index) ----
                        bf16x4 hb[DEPTH];
#pragma unroll
                        for (int p = 0; p < DEPTH; ++p) {
                            int ip = base + p;
                            ip = (ip < cnt) ? ip : (cnt - 1);           // uniform clamp
                            const int s = __builtin_amdgcn_readlane(rv, ip);
                            hb[p] = *(const bf16x4*)(hin + ((size_t)s << 8) + lane * 4);
                        }
                        // ---- consume (uniform guard; no lane divergence) ----
#pragma unroll
                        for (int p = 0; p < DEPTH; ++p) {
                            if (base + p < cnt) {                       // wave-uniform
                                const int t = __builtin_amdgcn_readlane(pv, base + p) >> 20;
                                if (t != cur) {
                                    if (cur >= 0) {
                                        const float inv = readlane_f(ivreg, cur);
                                        bf16x4 o;
                                        o.x = (bf16)(a0 * inv); o.y = (bf16)(a1 * inv);
                                        o.z = (bf16)(a2 * inv); o.w = (bf16)(a3 * inv);
                                        const int row = rbase + cur;
                                        const int unit = row * 32 + ((lane >> 1) ^ (row & 7));
                                        *(bf16x4*)&As[unit * 8 + (lane & 1) * 4] = o;
                                    }
                                    cur = t; a0 = a1 = a2 = a3 = 0.f;
                                }
                                a0 += (float)hb[p].x; a1 += (float)hb[p].y;
                                a2 += (float)hb[p].z; a3 += (float)hb[p].w;
                            }
                        }
                    }
                    st += cnt;
                }
                if (cur >= 0) {
                    const float inv = readlane_f(ivreg, cur);
                    bf16x4 o;
                    o.x = (bf16)(a0 * inv); o.y = (bf16)(a1 * inv);
                    o.z = (bf16)(a2 * inv); o.w = (bf16)(a3 * inv);
                    const int row = rbase + cur;
                    const int unit = row * 32 + ((lane >> 1) ^ (row & 7));
                    *(bf16x4*)&As[unit * 8 + (lane & 1) * 4] = o;
                }
            }
        }

        __syncthreads();   // As ready for all waves

        // ---- MFMA: 16 k-steps of 16; B frags = contiguous 1KB reads from Wfrag ----
        const bf16* const wseg = Wfrag + ((size_t)((w * 7 + seg) * 16) * 2 * 64) * 8;
#pragma unroll
        for (int step = 0; step < 16; ++step) {
            bf16x8 b0 = *(const bf16x8*)(wseg + ((size_t)(step * 2 + 0) * 64 + lane) * 8);
            bf16x8 b1 = *(const bf16x8*)(wseg + ((size_t)(step * 2 + 1) * 64 + lane) * 8);
            const int ku = step * 2 + lhi;
            bf16x8 a0 = *(const bf16x8*)&As[(l31 * 32 + (ku ^ (l31 & 7))) * 8];
            bf16x8 a1 = *(const bf16x8*)&As[((32 + l31) * 32 + (ku ^ (l31 & 7))) * 8];
            acc[0][0] = __builtin_amdgcn_mfma_f32_32x32x16_bf16(a0, b0, acc[0][0], 0, 0, 0);
            acc[0][1] = __builtin_amdgcn_mfma_f32_32x32x16_bf16(a0, b1, acc[0][1], 0, 0, 0);
            acc[1][0] = __builtin_amdgcn_mfma_f32_32x32x16_bf16(a1, b0, acc[1][0], 0, 0, 0);
            acc[1][1] = __builtin_amdgcn_mfma_f32_32x32x16_bf16(a1, b1, acc[1][1], 0, 0, 0);
        }
    }

    // ---- epilogue ----
    float bcol[2];
#pragma unroll
    for (int ct = 0; ct < 2; ++ct) bcol[ct] = bias[w * 64 + ct * 32 + l31];

    if constexpr (POOL) {
        // fused mean-pool into XCD-sharded buffer (blockIdx&7): 8x less same-address
        // atomic contention; mlp sums the shards.
        float* pshard = pooled + (size_t)(blockIdx.x & (NSHARD - 1)) * NGR * HIDD;
        __syncthreads();
        int* bidArr = (int*)As;
        if (tid < 64) {
            const int r = m0 + tid;
            bidArr[tid] = (r < NN) ? batch_ids[r] : -1;
        }
        __syncthreads();
        const int last = (m0 + 63 < NN) ? 63 : (NN - 1 - m0);
        const int glo = bidArr[0];
        const int ghi = bidArr[last];
        for (int g = glo; g <= ghi; ++g) {
            float s0 = 0.f, s1 = 0.f;
#pragma unroll
            for (int rt = 0; rt < 2; ++rt) {
#pragma unroll
                for (int reg = 0; reg < 16; ++reg) {
                    const int rl = rt * 32 + (reg & 3) + 8 * (reg >> 2) + 4 * lhi;
                    if (bidArr[rl] == g) {
                        s0 += fmaxf(acc[rt][0][reg] + bcol[0], 0.0f);
                        s1 += fmaxf(acc[rt][1][reg] + bcol[1], 0.0f);
                    }
                }
            }
            s0 += __shfl_xor(s0, 32);
            s1 += __shfl_xor(s1, 32);
            if (lhi == 0) {
                atomicAdd(&pshard[g * HIDD + w * 64 + l31], s0);
                atomicAdd(&pshard[g * HIDD + w * 64 + 32 + l31], s1);
            }
        }
    } else {
#pragma unroll
        for (int rt = 0; rt < 2; ++rt) {
#pragma unroll
            for (int reg = 0; reg < 16; ++reg) {
                const int row = m0 + rt * 32 + (reg & 3) + 8 * (reg >> 2) + 4 * lhi;
                if (row < NN) {
#pragma unroll
                    for (int ct = 0; ct < 2; ++ct) {
                        const int col = w * 64 + ct * 32 + l31;
                        float v = acc[rt][ct][reg] + bcol[ct];
                        hout[((size_t)row << 8) + col] = (bf16)fmaxf(v, 0.0f);
                    }
                }
            }
        }
    }
}

// ---------------- MLP head (sums pooled shards) ----------------
__global__ __launch_bounds__(256)
void mlp_kernel(const float* __restrict__ pooled, const float* __restrict__ cnt,
                const float* __restrict__ pW1, const float* __restrict__ pb1,
                const float* __restrict__ pW2, const float* __restrict__ pb2,
                float* __restrict__ out)
{
    const int g = blockIdx.x;
    const int d = threadIdx.x;
    __shared__ float pn[HIDD];
    __shared__ float mid[HIDD];
    float c = fmaxf(cnt[g], 1.0f);
    float sacc = 0.f;
#pragma unroll
    for (int x = 0; x < NSHARD; ++x)
        sacc += pooled[(size_t)x * NGR * HIDD + g * HIDD + d];
    pn[d] = sacc / c;
    __syncthreads();
    float s = pb1[d];
    for (int k = 0; k < HIDD; ++k) s = fmaf(pn[k], pW1[k * HIDD + d], s);
    mid[d] = fmaxf(s, 0.0f);
    __syncthreads();
    float s2 = pb2[d];
    for (int k = 0; k < HIDD; ++k) s2 = fmaf(mid[k], pW2[k * HIDD + d], s2);
    out[g * HIDD + d] = s2;
}

extern "C" void kernel_launch(void* const* d_in, const int* in_sizes, int n_in,
                              void* d_out, int out_size, void* d_ws, size_t ws_size,
                              hipStream_t stream)
{
    const int*   x_type    = (const int*)d_in[0];
    const int*   x_sub     = (const int*)d_in[1];
    const int*   edges     = (const int*)d_in[2];
    const int*   batch_ids = (const int*)d_in[3];
    const float* type_emb  = (const float*)d_in[5];
    const float* sub_emb   = (const float*)d_in[6];
    const float* W_rel0    = (const float*)d_in[7];
    const float* W_self0   = (const float*)d_in[8];
    const float* b0        = (const float*)d_in[9];
    const float* W_rel1    = (const float*)d_in[10];
    const float* W_self1   = (const float*)d_in[11];
    const float* b1        = (const float*)d_in[12];
    const float* pW1       = (const float*)d_in[13];
    const float* pb1       = (const float*)d_in[14];
    const float* pW2       = (const float*)d_in[15];
    const float* pb2       = (const float*)d_in[16];
    float* out = (float*)d_out;

    // workspace carve-up (~65 MB)
    char* p = (char*)d_ws;
    auto carve = [&](size_t bytes) { char* q = p; p += (bytes + 255) & ~255ull; return q; };
    bf16*  h1     = (bf16*) carve((size_t)NN * HIDD * sizeof(bf16));     // layer-0 out
    bf16*  Wf0    = (bf16*) carve((size_t)WFRAG_ELEMS * sizeof(bf16));
    bf16*  Wf1    = (bf16*) carve((size_t)WFRAG_ELEMS * sizeof(bf16));
    bf16*  etab   = (bf16*) carve((size_t)1024 * 256 * sizeof(bf16));    // 512 KB
    float* invdeg = (float*)carve((size_t)NN * sizeof(float));
    int*   hist   = (int*)  carve((size_t)NKEY * sizeof(int));
    int*   offs   = (int*)  carve((size_t)(NKEY + 1) * sizeof(int));
    int*   cursor = (int*)  carve((size_t)NKEY * sizeof(int));
    int*   bsum   = (int*)  carve(2048 * sizeof(int));
    int*   epack  = (int*)  carve((size_t)NEDGT * sizeof(int));
    int*   epack2 = (int*)  carve((size_t)NEDGT * sizeof(int));
    float* pooled = (float*)carve((size_t)NSHARD * NGR * HIDD * sizeof(float));  // 1 MB
    float* cnt    = (float*)carve((size_t)NGR * sizeof(float));          // adjacent

    hipMemsetAsync(hist, 0, (size_t)NKEY * sizeof(int), stream);
    hipMemsetAsync(pooled, 0, (size_t)(NSHARD * NGR * HIDD + NGR) * sizeof(float), stream);

    const int NB0 = (NKEY + 2047) / 2048;  // 293
    hist_kernel<<<(NEDGT + 255) / 256, 256, 0, stream>>>(edges, hist);
    scan_l0<<<NB0, 256, 0, stream>>>(hist, offs, bsum, NKEY);
    scan_l1<<<1, 256, 0, stream>>>(bsum, NB0);
    scan_l2<<<(NKEY + 255) / 256, 256, 0, stream>>>(offs, cursor, bsum, hist, invdeg,
                                                    batch_ids, cnt, NKEY);
    scatter_kernel<<<(NEDGT + 255) / 256, 256, 0, stream>>>(edges, cursor, x_type, x_sub,
                                                            epack, epack2);
    build_etab<<<1024, 256, 0, stream>>>(type_emb, sub_emb, etab);

    dim3 wgrid(7, 16, 2);
    build_wfrag<<<wgrid, 256, 0, stream>>>(W_rel0, W_self0, W_rel1, W_self1, Wf0, Wf1);

    const int FGRID = (NN + 63) / 64;   // 1563
    rgcn_fused<true, false><<<FGRID, 256, 0, stream>>>(
        etab, x_type, x_sub, type_emb, sub_emb,
        Wf0, b0, invdeg, offs, epack, epack2, batch_ids, pooled, h1);
    rgcn_fused<false, true><<<FGRID, 256, 0, stream>>>(
        h1, x_type, x_sub, type_emb, sub_emb,
        Wf1, b1, invdeg, offs, epack, epack2, batch_ids, pooled, nullptr);

    mlp_kernel<<<NGR, 256, 0, stream>>>(pooled, cnt, pW1, pb1, pW2, pb2, out);
}

// Round 17
// 533.441 us; speedup vs baseline: 1.0189x; 1.0189x over previous
//
#include <hip/hip_runtime.h>

#define NN    100000   // nodes
#define NEDGE 100000   // edges per relation
#define NRELS 6
#define HIDD  256
#define NGR   128      // graphs
#define NKEY  (NRELS * NN)        // 600000 (rel,tgt) keys
#define NEDGT (NRELS * NEDGE)     // 600000 edges total
#define WFRAG_ELEMS (4 * 7 * 16 * 2 * 64 * 8)   // 458752 bf16 per layer
#define SMASK 0xFFFFF             // src field of epack (src < 2^17)
#define NSHARD 8                  // pooled shards (atomic de-contention)

typedef __bf16 bf16;
typedef __bf16 bf16x4 __attribute__((ext_vector_type(4)));
typedef __bf16 bf16x8 __attribute__((ext_vector_type(8)));
typedef float  f32x4  __attribute__((ext_vector_type(4)));
typedef float  f32x16 __attribute__((ext_vector_type(16)));

__device__ __forceinline__ float readlane_f(float v, int sl) {
    return __int_as_float(__builtin_amdgcn_readlane(__float_as_int(v), sl));
}

// ================= CSR build (key = rel*NN + tgt) =================
__global__ __launch_bounds__(256)
void hist_kernel(const int* __restrict__ edges, int* __restrict__ hist)
{
    int i = blockIdx.x * 256 + threadIdx.x;
    if (i >= NEDGT) return;
    int r = i / NEDGE;
    int e = i - r * NEDGE;
    int t = edges[r * (2 * NEDGE) + NEDGE + e];
    atomicAdd(&hist[r * NN + t], 1);
}

__global__ __launch_bounds__(256)
void scan_l0(const int* __restrict__ in, int* __restrict__ out, int* __restrict__ bsum, int n)
{
    __shared__ int sdata[256];
    const int t = threadIdx.x;
    const int base = blockIdx.x * 2048 + t * 8;
    int v[8]; int s = 0;
#pragma unroll
    for (int i = 0; i < 8; ++i) {
        int idx = base + i;
        int x = (idx < n) ? in[idx] : 0;
        v[i] = s; s += x;
    }
    sdata[t] = s;
    __syncthreads();
    for (int off = 1; off < 256; off <<= 1) {
        int y = (t >= off) ? sdata[t - off] : 0;
        __syncthreads();
        sdata[t] += y;
        __syncthreads();
    }
    int excl = sdata[t] - s;
#pragma unroll
    for (int i = 0; i < 8; ++i) {
        int idx = base + i;
        if (idx < n) out[idx] = excl + v[i];
    }
    if (t == 0) bsum[blockIdx.x] = sdata[255];
}

__global__ __launch_bounds__(256)
void scan_l1(int* __restrict__ bsum, int n)
{
    __shared__ int sdata[256];
    const int t = threadIdx.x;
    const int base = t * 8;
    int v[8]; int s = 0;
#pragma unroll
    for (int i = 0; i < 8; ++i) {
        int idx = base + i;
        int x = (idx < n) ? bsum[idx] : 0;
        v[i] = s; s += x;
    }
    sdata[t] = s;
    __syncthreads();
    for (int off = 1; off < 256; off <<= 1) {
        int y = (t >= off) ? sdata[t - off] : 0;
        __syncthreads();
        sdata[t] += y;
        __syncthreads();
    }
    int excl = sdata[t] - s;
#pragma unroll
    for (int i = 0; i < 8; ++i) {
        int idx = base + i;
        if (idx < n) bsum[idx] = excl + v[i];
    }
}

// add block sums; cursor copy; sentinel; fused invdeg; fused graph-size counts
__global__ __launch_bounds__(256)
void scan_l2(int* __restrict__ offs, int* __restrict__ cursor, const int* __restrict__ bsum,
             const int* __restrict__ hist, float* __restrict__ invdeg,
             const int* __restrict__ batch_ids, float* __restrict__ cnt, int n)
{
    int idx = blockIdx.x * 256 + threadIdx.x;
    if (idx == 0) offs[NKEY] = NEDGT;

    // graph-size counts (runs within each wave; batch_ids sorted)
    {
        const int lane = threadIdx.x & 63;
        const bool valid = idx < NN;
        const int gv = valid ? batch_ids[idx] : -1;
        const int gprev = __shfl(gv, lane - 1);
        const bool head = valid && (lane == 0 || gv != gprev);
        const bool stop = head || !valid;
        const unsigned long long mask = __ballot(stop);
        if (head) {
            unsigned long long above = (lane == 63) ? 0ull : (mask >> (lane + 1));
            const int next = above ? (lane + 1 + __builtin_ctzll(above)) : 64;
            atomicAdd(&cnt[gv], (float)(next - lane));
        }
    }

    if (idx < NN) {
        int d = 0;
#pragma unroll
        for (int r = 0; r < NRELS; ++r) d += hist[r * NN + idx];
        invdeg[idx] = 1.0f / fmaxf((float)d, 1.0f);
    }
    if (idx >= n) return;
    int v = offs[idx] + bsum[idx >> 11];
    offs[idx] = v;
    cursor[idx] = v;
}

// epack = src | ((tgt & 63) << 20)  (block-local row, 64-row blocks);
// epack2 = xt[src]*256 + xs[src] (etab row)
__global__ __launch_bounds__(256)
void scatter_kernel(const int* __restrict__ edges, int* __restrict__ cursor,
                    const int* __restrict__ xt, const int* __restrict__ xs,
                    int* __restrict__ epack, int* __restrict__ epack2)
{
    int i = blockIdx.x * 256 + threadIdx.x;
    if (i >= NEDGT) return;
    int r = i / NEDGE;
    int e = i - r * NEDGE;
    int s = edges[r * (2 * NEDGE) + e];
    int t = edges[r * (2 * NEDGE) + NEDGE + e];
    int pos = atomicAdd(&cursor[r * NN + t], 1);
    epack[pos] = s | ((t & 63) << 20);
    epack2[pos] = xt[s] * 256 + xs[s];
}

// ---------------- etab[c][f]: concat embedding for combo c = xt*256+xs (bf16) ----------------
__global__ __launch_bounds__(256)
void build_etab(const float* __restrict__ temb, const float* __restrict__ semb,
                bf16* __restrict__ etab)
{
    const int c = blockIdx.x;          // 0..1023
    const int f = threadIdx.x;         // 0..255
    const int t = c >> 8, s = c & 255;
    float v = (f < 128) ? temb[t * 128 + f] : semb[s * 128 + (f - 128)];
    etab[c * 256 + f] = (bf16)v;
}

// ---------------- Wfrag: B pre-swizzled into MFMA fragment order ----------------
// layout unchanged from R12-16; consumer wave w (0..7) maps to (wOld=w>>1, ct=w&1)
__global__ __launch_bounds__(256)
void build_wfrag(const float* __restrict__ Wr0, const float* __restrict__ Ws0,
                 const float* __restrict__ Wr1, const float* __restrict__ Ws1,
                 bf16* __restrict__ Wf0, bf16* __restrict__ Wf1)
{
    const int seg = blockIdx.x;     // 0..6
    const int step = blockIdx.y;    // 0..15
    const int layer = blockIdx.z;   // 0..1
    const int tid = threadIdx.x;
    const int w = tid >> 6;
    const int lane = tid & 63;
    const int l31 = lane & 31;
    const int lhi = lane >> 5;

    const float* Wr = layer ? Wr1 : Wr0;
    const float* Ws = layer ? Ws1 : Ws0;
    const float* src = (seg < 6) ? (Wr + ((size_t)seg << 16)) : Ws;
    bf16* Wf = layer ? Wf1 : Wf0;

    const int kb = step * 16 + lhi * 8;   // segment-local k
#pragma unroll
    for (int ct = 0; ct < 2; ++ct) {
        const int n = w * 64 + ct * 32 + l31;
        bf16x8 o;
#pragma unroll
        for (int j = 0; j < 8; ++j)
            o[j] = (bf16)src[(size_t)(kb + j) * 256 + n];
        const size_t fb_idx = (size_t)(((w * 7 + seg) * 16 + step) * 2 + ct) * 64 + lane;
        *(bf16x8*)(Wf + fb_idx * 8) = o;
    }
}

// ---------------- fused RGCN layer, 512-thread blocks ----------------
// 8 waves/block; wave w: 32 output cols (wc = (w>>1)*64 + (w&1)*32), all 64 rows;
// wave gathers rows w*8..+8 (contiguous CSR range). acc = 32 AGPRs -> arch+acc
// fits the 128-reg cap -> 4 waves/EU = 16 waves/CU (2x R16's residency; R14 showed
// the old 64-AGPR tile spills at this cap). Same gather structure as R12/R16:
// unconditional clamped DEPTH=16 bursts; single-level row source (L0: etab via
// epack2; L1: h1 via epack&SMASK); B frags = coalesced 1KB Wfrag reads (L2-hot).
// POOL epilogue: fused mean-pool into XCD-sharded buffers.
template<bool L0, bool POOL>
__global__ __launch_bounds__(512, 4)
void rgcn_fused(const bf16* __restrict__ hin,
                const int* __restrict__ xt, const int* __restrict__ xs,
                const float* __restrict__ temb, const float* __restrict__ semb,
                const bf16* __restrict__ Wfrag, const float* __restrict__ bias,
                const float* __restrict__ invdeg, const int* __restrict__ offs,
                const int* __restrict__ epack, const int* __restrict__ epack2,
                const int* __restrict__ batch_ids,
                float* __restrict__ pooled, bf16* __restrict__ hout)
{
    constexpr int DEPTH = 16;
    const int m0 = blockIdx.x * 64;
    const int tid = threadIdx.x;
    const int lane = tid & 63;
    const int w = tid >> 6;                   // 0..7
    const int l31 = lane & 31;
    const int lhi = lane >> 5;
    const int rbase = w * 8;                  // this wave's first block-local row
    const int wc = (w >> 1) * 64 + (w & 1) * 32;   // this wave's first col

    __shared__ __align__(16) bf16 As[64 * HIDD];   // 32 KB (shared by 8 waves)

    f32x16 acc[2] = {};   // rows 0-31 / 32-63 x this wave's 32 cols

    // lane i (i&7) holds invdeg of block-local row rbase + (i&7); readlane at flush
    int ivrow = m0 + rbase + (lane & 7);
    if (ivrow >= NN) ivrow = NN - 1;
    const float ivreg = invdeg[ivrow];

    for (int seg = 0; seg < 7; ++seg) {
        __syncthreads();   // previous seg's MFMA reads of As complete

        // ---- zero this wave's 8 rows (2 rows per z-iter) ----
#pragma unroll
        for (int z = 0; z < 4; ++z) {
            const int row = rbase + z * 2 + lhi;
            const int unit = row * 32 + (l31 ^ (row & 7));
            *(bf16x8*)&As[unit * 8] = (bf16x8)(bf16)0.0f;
        }

        if (seg == 6) {
            // ---- self segment: copy h rows / inline embed ----
#pragma unroll
            for (int z = 0; z < 4; ++z) {
                const int row = rbase + z * 2 + lhi;
                const int gr = m0 + row;
                if (gr < NN) {
                    bf16x8 o;
                    if (L0) {
                        const int f0 = l31 * 8;
                        const float* src = (f0 < 128) ? (temb + xt[gr] * 128 + f0)
                                                      : (semb + xs[gr] * 128 + (f0 - 128));
                        f32x4 x0 = *(const f32x4*)src;
                        f32x4 x1 = *(const f32x4*)(src + 4);
                        o[0] = (bf16)x0[0]; o[1] = (bf16)x0[1];
                        o[2] = (bf16)x0[2]; o[3] = (bf16)x0[3];
                        o[4] = (bf16)x1[0]; o[5] = (bf16)x1[1];
                        o[6] = (bf16)x1[2]; o[7] = (bf16)x1[3];
                    } else {
                        o = *(const bf16x8*)(hin + ((size_t)gr << 8) + l31 * 8);
                    }
                    const int unit = row * 32 + (l31 ^ (row & 7));
                    *(bf16x8*)&As[unit * 8] = o;
                }
            }
        } else {
            // ---- aggregation for rows [m0+rbase, +8) ----
            const int gr0 = m0 + rbase;
            if (gr0 < NN) {
                const int rend = (gr0 + 8 < NN) ? (gr0 + 8) : NN;
                int st = offs[seg * NN + gr0];
                const int en = offs[seg * NN + rend];

                float a0 = 0.f, a1 = 0.f, a2 = 0.f, a3 = 0.f;
                int cur = -1;   // wave-uniform block-local row

                while (st < en) {
                    const int cnt = (en - st < 64) ? (en - st) : 64;
                    const int idx = st + ((lane < cnt) ? lane : (cnt - 1));
                    const int pv = epack[idx];                 // tgt meta (clamped)
                    const int rv = L0 ? epack2[idx]            // etab row
                                      : (pv & SMASK);          // h row

                    for (int base = 0; base < cnt; base += DEPTH) {
                        // ---- unconditional burst of DEPTH gathers (clamped index) ----
                        bf16x4 hb[DEPTH];
#pragma unroll
                        for (int p = 0; p < DEPTH; ++p) {
                            int ip = base + p;
                            ip = (ip < cnt) ? ip : (cnt - 1);           // uniform clamp
                            const int s = __builtin_amdgcn_readlane(rv, ip);
                            hb[p] = *(const bf16x4*)(hin + ((size_t)s << 8) + lane * 4);
                        }
                        // ---- consume (uniform guard; no lane divergence) ----
#pragma unroll
                        for (int p = 0; p < DEPTH; ++p) {
                            if (base + p < cnt) {                       // wave-uniform
                                const int t = (__builtin_amdgcn_readlane(pv, base + p) >> 20) & 63;
                                if (t != cur) {
                                    if (cur >= 0) {
                                        const float inv = readlane_f(ivreg, cur - rbase);
                                        bf16x4 o;
                                        o.x = (bf16)(a0 * inv); o.y = (bf16)(a1 * inv);
                                        o.z = (bf16)(a2 * inv); o.w = (bf16)(a3 * inv);
                                        const int unit = cur * 32 + ((lane >> 1) ^ (cur & 7));
                                        *(bf16x4*)&As[unit * 8 + (lane & 1) * 4] = o;
                                    }
                                    cur = t; a0 = a1 = a2 = a3 = 0.f;
                                }
                                a0 += (float)hb[p].x; a1 += (float)hb[p].y;
                                a2 += (float)hb[p].z; a3 += (float)hb[p].w;
                            }
                        }
                    }
                    st += cnt;
                }
                if (cur >= 0) {
                    const float inv = readlane_f(ivreg, cur - rbase);
                    bf16x4 o;
                    o.x = (bf16)(a0 * inv); o.y = (bf16)(a1 * inv);
                    o.z = (bf16)(a2 * inv); o.w = (bf16)(a3 * inv);
                    const int unit = cur * 32 + ((lane >> 1) ^ (cur & 7));
                    *(bf16x4*)&As[unit * 8 + (lane & 1) * 4] = o;
                }
            }
        }

        __syncthreads();   // As ready for all waves

        // ---- MFMA: 16 k-steps of 16; B frag = one contiguous 1KB read per step ----
        const bf16* const wseg = Wfrag + ((size_t)(((w >> 1) * 7 + seg) * 16) * 2 * 64) * 8;
#pragma unroll
        for (int step = 0; step < 16; ++step) {
            bf16x8 b0 = *(const bf16x8*)(wseg + ((size_t)(step * 2 + (w & 1)) * 64 + lane) * 8);
            const int ku = step * 2 + lhi;
            bf16x8 a0 = *(const bf16x8*)&As[(l31 * 32 + (ku ^ (l31 & 7))) * 8];
            bf16x8 a1 = *(const bf16x8*)&As[((32 + l31) * 32 + (ku ^ (l31 & 7))) * 8];
            acc[0] = __builtin_amdgcn_mfma_f32_32x32x16_bf16(a0, b0, acc[0], 0, 0, 0);
            acc[1] = __builtin_amdgcn_mfma_f32_32x32x16_bf16(a1, b0, acc[1], 0, 0, 0);
        }
    }

    // ---- epilogue ----
    const float bcol = bias[wc + l31];

    if constexpr (POOL) {
        // fused mean-pool into XCD-sharded buffer (blockIdx&7)
        float* pshard = pooled + (size_t)(blockIdx.x & (NSHARD - 1)) * NGR * HIDD;
        __syncthreads();
        int* bidArr = (int*)As;
        if (tid < 64) {
            const int r = m0 + tid;
            bidArr[tid] = (r < NN) ? batch_ids[r] : -1;
        }
        __syncthreads();
        const int last = (m0 + 63 < NN) ? 63 : (NN - 1 - m0);
        const int glo = bidArr[0];
        const int ghi = bidArr[last];
        for (int g = glo; g <= ghi; ++g) {
            float s0 = 0.f;
#pragma unroll
            for (int rt = 0; rt < 2; ++rt) {
#pragma unroll
                for (int reg = 0; reg < 16; ++reg) {
                    const int rl = rt * 32 + (reg & 3) + 8 * (reg >> 2) + 4 * lhi;
                    if (bidArr[rl] == g)
                        s0 += fmaxf(acc[rt][reg] + bcol, 0.0f);
                }
            }
            s0 += __shfl_xor(s0, 32);
            if (lhi == 0)
                atomicAdd(&pshard[g * HIDD + wc + l31], s0);
        }
    } else {
#pragma unroll
        for (int rt = 0; rt < 2; ++rt) {
#pragma unroll
            for (int reg = 0; reg < 16; ++reg) {
                const int row = m0 + rt * 32 + (reg & 3) + 8 * (reg >> 2) + 4 * lhi;
                if (row < NN) {
                    const int col = wc + l31;
                    float v = acc[rt][reg] + bcol;
                    hout[((size_t)row << 8) + col] = (bf16)fmaxf(v, 0.0f);
                }
            }
        }
    }
}

// ---------------- MLP head (sums pooled shards) ----------------
__global__ __launch_bounds__(256)
void mlp_kernel(const float* __restrict__ pooled, const float* __restrict__ cnt,
                const float* __restrict__ pW1, const float* __restrict__ pb1,
                const float* __restrict__ pW2, const float* __restrict__ pb2,
                float* __restrict__ out)
{
    const int g = blockIdx.x;
    const int d = threadIdx.x;
    __shared__ float pn[HIDD];
    __shared__ float mid[HIDD];
    float c = fmaxf(cnt[g], 1.0f);
    float sacc = 0.f;
#pragma unroll
    for (int x = 0; x < NSHARD; ++x)
        sacc += pooled[(size_t)x * NGR * HIDD + g * HIDD + d];
    pn[d] = sacc / c;
    __syncthreads();
    float s = pb1[d];
    for (int k = 0; k < HIDD; ++k) s = fmaf(pn[k], pW1[k * HIDD + d], s);
    mid[d] = fmaxf(s, 0.0f);
    __syncthreads();
    float s2 = pb2[d];
    for (int k = 0; k < HIDD; ++k) s2 = fmaf(mid[k], pW2[k * HIDD + d], s2);
    out[g * HIDD + d] = s2;
}

extern "C" void kernel_launch(void* const* d_in, const int* in_sizes, int n_in,
                              void* d_out, int out_size, void* d_ws, size_t ws_size,
                              hipStream_t stream)
{
    const int*   x_type    = (const int*)d_in[0];
    const int*   x_sub     = (const int*)d_in[1];
    const int*   edges     = (const int*)d_in[2];
    const int*   batch_ids = (const int*)d_in[3];
    const float* type_emb  = (const float*)d_in[5];
    const float* sub_emb   = (const float*)d_in[6];
    const float* W_rel0    = (const float*)d_in[7];
    const float* W_self0   = (const float*)d_in[8];
    const float* b0        = (const float*)d_in[9];
    const float* W_rel1    = (const float*)d_in[10];
    const float* W_self1   = (const float*)d_in[11];
    const float* b1        = (const float*)d_in[12];
    const float* pW1       = (const float*)d_in[13];
    const float* pb1       = (const float*)d_in[14];
    const float* pW2       = (const float*)d_in[15];
    const float* pb2       = (const float*)d_in[16];
    float* out = (float*)d_out;

    // workspace carve-up (~65 MB)
    char* p = (char*)d_ws;
    auto carve = [&](size_t bytes) { char* q = p; p += (bytes + 255) & ~255ull; return q; };
    bf16*  h1     = (bf16*) carve((size_t)NN * HIDD * sizeof(bf16));     // layer-0 out
    bf16*  Wf0    = (bf16*) carve((size_t)WFRAG_ELEMS * sizeof(bf16));
    bf16*  Wf1    = (bf16*) carve((size_t)WFRAG_ELEMS * sizeof(bf16));
    bf16*  etab   = (bf16*) carve((size_t)1024 * 256 * sizeof(bf16));    // 512 KB
    float* invdeg = (float*)carve((size_t)NN * sizeof(float));
    int*   hist   = (int*)  carve((size_t)NKEY * sizeof(int));
    int*   offs   = (int*)  carve((size_t)(NKEY + 1) * sizeof(int));
    int*   cursor = (int*)  carve((size_t)NKEY * sizeof(int));
    int*   bsum   = (int*)  carve(2048 * sizeof(int));
    int*   epack  = (int*)  carve((size_t)NEDGT * sizeof(int));
    int*   epack2 = (int*)  carve((size_t)NEDGT * sizeof(int));
    float* pooled = (float*)carve((size_t)NSHARD * NGR * HIDD * sizeof(float));  // 1 MB
    float* cnt    = (float*)carve((size_t)NGR * sizeof(float));          // adjacent

    hipMemsetAsync(hist, 0, (size_t)NKEY * sizeof(int), stream);
    hipMemsetAsync(pooled, 0, (size_t)(NSHARD * NGR * HIDD + NGR) * sizeof(float), stream);

    const int NB0 = (NKEY + 2047) / 2048;  // 293
    hist_kernel<<<(NEDGT + 255) / 256, 256, 0, stream>>>(edges, hist);
    scan_l0<<<NB0, 256, 0, stream>>>(hist, offs, bsum, NKEY);
    scan_l1<<<1, 256, 0, stream>>>(bsum, NB0);
    scan_l2<<<(NKEY + 255) / 256, 256, 0, stream>>>(offs, cursor, bsum, hist, invdeg,
                                                    batch_ids, cnt, NKEY);
    scatter_kernel<<<(NEDGT + 255) / 256, 256, 0, stream>>>(edges, cursor, x_type, x_sub,
                                                            epack, epack2);
    build_etab<<<1024, 256, 0, stream>>>(type_emb, sub_emb, etab);

    dim3 wgrid(7, 16, 2);
    build_wfrag<<<wgrid, 256, 0, stream>>>(W_rel0, W_self0, W_rel1, W_self1, Wf0, Wf1);

    const int FGRID = (NN + 63) / 64;   // 1563
    rgcn_fused<true, false><<<FGRID, 512, 0, stream>>>(
        etab, x_type, x_sub, type_emb, sub_emb,
        Wf0, b0, invdeg, offs, epack, epack2, batch_ids, pooled, h1);
    rgcn_fused<false, true><<<FGRID, 512, 0, stream>>>(
        h1, x_type, x_sub, type_emb, sub_emb,
        Wf1, b1, invdeg, offs, epack, epack2, batch_ids, pooled, nullptr);

    mlp_kernel<<<NGR, 256, 0, stream>>>(pooled, cnt, pW1, pb1, pW2, pb2, out);
}

// Round 18
// 498.980 us; speedup vs baseline: 1.0893x; 1.0691x over previous
//
#include <hip/hip_runtime.h>

#define NN    100000   // nodes
#define NEDGE 100000   // edges per relation
#define NRELS 6
#define HIDD  256
#define NGR   128      // graphs
#define NKEY  (NRELS * NN)        // 600000 (rel,tgt) keys
#define NEDGT (NRELS * NEDGE)     // 600000 edges total
#define WFRAG_ELEMS (4 * 7 * 16 * 2 * 64 * 8)   // 458752 bf16 per layer
#define SMASK 0xFFFFF             // src field of epack (src < 2^17)
#define NSHARD 8                  // pooled shards (atomic de-contention)

typedef __bf16 bf16;
typedef __bf16 bf16x4 __attribute__((ext_vector_type(4)));
typedef __bf16 bf16x8 __attribute__((ext_vector_type(8)));
typedef float  f32x4  __attribute__((ext_vector_type(4)));
typedef float  f32x16 __attribute__((ext_vector_type(16)));

template<int N> struct ICT { static constexpr int B = N; };

__device__ __forceinline__ float readlane_f(float v, int sl) {
    return __int_as_float(__builtin_amdgcn_readlane(__float_as_int(v), sl));
}

// ================= CSR build (key = rel*NN + tgt) =================
__global__ __launch_bounds__(256)
void hist_kernel(const int* __restrict__ edges, int* __restrict__ hist)
{
    int i = blockIdx.x * 256 + threadIdx.x;
    if (i >= NEDGT) return;
    int r = i / NEDGE;
    int e = i - r * NEDGE;
    int t = edges[r * (2 * NEDGE) + NEDGE + e];
    atomicAdd(&hist[r * NN + t], 1);
}

__global__ __launch_bounds__(256)
void scan_l0(const int* __restrict__ in, int* __restrict__ out, int* __restrict__ bsum, int n)
{
    __shared__ int sdata[256];
    const int t = threadIdx.x;
    const int base = blockIdx.x * 2048 + t * 8;
    int v[8]; int s = 0;
#pragma unroll
    for (int i = 0; i < 8; ++i) {
        int idx = base + i;
        int x = (idx < n) ? in[idx] : 0;
        v[i] = s; s += x;
    }
    sdata[t] = s;
    __syncthreads();
    for (int off = 1; off < 256; off <<= 1) {
        int y = (t >= off) ? sdata[t - off] : 0;
        __syncthreads();
        sdata[t] += y;
        __syncthreads();
    }
    int excl = sdata[t] - s;
#pragma unroll
    for (int i = 0; i < 8; ++i) {
        int idx = base + i;
        if (idx < n) out[idx] = excl + v[i];
    }
    if (t == 0) bsum[blockIdx.x] = sdata[255];
}

__global__ __launch_bounds__(256)
void scan_l1(int* __restrict__ bsum, int n)
{
    __shared__ int sdata[256];
    const int t = threadIdx.x;
    const int base = t * 8;
    int v[8]; int s = 0;
#pragma unroll
    for (int i = 0; i < 8; ++i) {
        int idx = base + i;
        int x = (idx < n) ? bsum[idx] : 0;
        v[i] = s; s += x;
    }
    sdata[t] = s;
    __syncthreads();
    for (int off = 1; off < 256; off <<= 1) {
        int y = (t >= off) ? sdata[t - off] : 0;
        __syncthreads();
        sdata[t] += y;
        __syncthreads();
    }
    int excl = sdata[t] - s;
#pragma unroll
    for (int i = 0; i < 8; ++i) {
        int idx = base + i;
        if (idx < n) bsum[idx] = excl + v[i];
    }
}

// add block sums; cursor copy; sentinel; fused invdeg; fused graph-size counts
__global__ __launch_bounds__(256)
void scan_l2(int* __restrict__ offs, int* __restrict__ cursor, const int* __restrict__ bsum,
             const int* __restrict__ hist, float* __restrict__ invdeg,
             const int* __restrict__ batch_ids, float* __restrict__ cnt, int n)
{
    int idx = blockIdx.x * 256 + threadIdx.x;
    if (idx == 0) offs[NKEY] = NEDGT;

    // graph-size counts (runs within each wave; batch_ids sorted)
    {
        const int lane = threadIdx.x & 63;
        const bool valid = idx < NN;
        const int gv = valid ? batch_ids[idx] : -1;
        const int gprev = __shfl(gv, lane - 1);
        const bool head = valid && (lane == 0 || gv != gprev);
        const bool stop = head || !valid;
        const unsigned long long mask = __ballot(stop);
        if (head) {
            unsigned long long above = (lane == 63) ? 0ull : (mask >> (lane + 1));
            const int next = above ? (lane + 1 + __builtin_ctzll(above)) : 64;
            atomicAdd(&cnt[gv], (float)(next - lane));
        }
    }

    if (idx < NN) {
        int d = 0;
#pragma unroll
        for (int r = 0; r < NRELS; ++r) d += hist[r * NN + idx];
        invdeg[idx] = 1.0f / fmaxf((float)d, 1.0f);
    }
    if (idx >= n) return;
    int v = offs[idx] + bsum[idx >> 11];
    offs[idx] = v;
    cursor[idx] = v;
}

// epack = src | ((tgt & 63) << 20); epack2 = xt[src]*256 + xs[src] (etab row)
__global__ __launch_bounds__(256)
void scatter_kernel(const int* __restrict__ edges, int* __restrict__ cursor,
                    const int* __restrict__ xt, const int* __restrict__ xs,
                    int* __restrict__ epack, int* __restrict__ epack2)
{
    int i = blockIdx.x * 256 + threadIdx.x;
    if (i >= NEDGT) return;
    int r = i / NEDGE;
    int e = i - r * NEDGE;
    int s = edges[r * (2 * NEDGE) + e];
    int t = edges[r * (2 * NEDGE) + NEDGE + e];
    int pos = atomicAdd(&cursor[r * NN + t], 1);
    epack[pos] = s | ((t & 63) << 20);
    epack2[pos] = xt[s] * 256 + xs[s];
}

// ---------------- etab[c][f]: concat embedding for combo c = xt*256+xs (bf16) ----------------
__global__ __launch_bounds__(256)
void build_etab(const float* __restrict__ temb, const float* __restrict__ semb,
                bf16* __restrict__ etab)
{
    const int c = blockIdx.x;          // 0..1023
    const int f = threadIdx.x;         // 0..255
    const int t = c >> 8, s = c & 255;
    float v = (f < 128) ? temb[t * 128 + f] : semb[s * 128 + (f - 128)];
    etab[c * 256 + f] = (bf16)v;
}

// ---------------- Wfrag: B pre-swizzled into MFMA fragment order ----------------
__global__ __launch_bounds__(256)
void build_wfrag(const float* __restrict__ Wr0, const float* __restrict__ Ws0,
                 const float* __restrict__ Wr1, const float* __restrict__ Ws1,
                 bf16* __restrict__ Wf0, bf16* __restrict__ Wf1)
{
    const int seg = blockIdx.x;     // 0..6
    const int step = blockIdx.y;    // 0..15
    const int layer = blockIdx.z;   // 0..1
    const int tid = threadIdx.x;
    const int w = tid >> 6;
    const int lane = tid & 63;
    const int l31 = lane & 31;
    const int lhi = lane >> 5;

    const float* Wr = layer ? Wr1 : Wr0;
    const float* Ws = layer ? Ws1 : Ws0;
    const float* src = (seg < 6) ? (Wr + ((size_t)seg << 16)) : Ws;
    bf16* Wf = layer ? Wf1 : Wf0;

    const int kb = step * 16 + lhi * 8;   // segment-local k
#pragma unroll
    for (int ct = 0; ct < 2; ++ct) {
        const int n = w * 64 + ct * 32 + l31;
        bf16x8 o;
#pragma unroll
        for (int j = 0; j < 8; ++j)
            o[j] = (bf16)src[(size_t)(kb + j) * 256 + n];
        const size_t fb_idx = (size_t)(((w * 7 + seg) * 16 + step) * 2 + ct) * 64 + lane;
        *(bf16x8*)(Wf + fb_idx * 8) = o;
    }
}

// ---------------- fused RGCN layer, 512-thread blocks, adaptive bursts ----------------
// 8 waves/block; wave w: 32 output cols, all 64 rows; wave gathers rows w*8..+8.
// Gather loads issued in ADAPTIVE EXACT bursts (16/8/4/2/1, uniform branches):
// no clamp-duplicate loads, no per-iteration consume guards (R17 wasted ~2x VALU
// on padding at mean cnt~8). Single-level row source (L0: etab via epack2; L1: h1
// via epack&SMASK); B frags = coalesced 1KB Wfrag reads (L2-hot). POOL epilogue:
// fused mean-pool into XCD-sharded buffers.
template<bool L0, bool POOL>
__global__ __launch_bounds__(512, 4)
void rgcn_fused(const bf16* __restrict__ hin,
                const int* __restrict__ xt, const int* __restrict__ xs,
                const float* __restrict__ temb, const float* __restrict__ semb,
                const bf16* __restrict__ Wfrag, const float* __restrict__ bias,
                const float* __restrict__ invdeg, const int* __restrict__ offs,
                const int* __restrict__ epack, const int* __restrict__ epack2,
                const int* __restrict__ batch_ids,
                float* __restrict__ pooled, bf16* __restrict__ hout)
{
    const int m0 = blockIdx.x * 64;
    const int tid = threadIdx.x;
    const int lane = tid & 63;
    const int w = tid >> 6;                   // 0..7
    const int l31 = lane & 31;
    const int lhi = lane >> 5;
    const int rbase = w * 8;                  // this wave's first block-local row
    const int wc = (w >> 1) * 64 + (w & 1) * 32;   // this wave's first col

    __shared__ __align__(16) bf16 As[64 * HIDD];   // 32 KB (shared by 8 waves)

    f32x16 acc[2] = {};   // rows 0-31 / 32-63 x this wave's 32 cols

    // lane i (i&7) holds invdeg of block-local row rbase + (i&7); readlane at flush
    int ivrow = m0 + rbase + (lane & 7);
    if (ivrow >= NN) ivrow = NN - 1;
    const float ivreg = invdeg[ivrow];

    for (int seg = 0; seg < 7; ++seg) {
        __syncthreads();   // previous seg's MFMA reads of As complete

        // ---- zero this wave's 8 rows ----
#pragma unroll
        for (int z = 0; z < 4; ++z) {
            const int row = rbase + z * 2 + lhi;
            const int unit = row * 32 + (l31 ^ (row & 7));
            *(bf16x8*)&As[unit * 8] = (bf16x8)(bf16)0.0f;
        }

        if (seg == 6) {
            // ---- self segment: copy h rows / inline embed ----
#pragma unroll
            for (int z = 0; z < 4; ++z) {
                const int row = rbase + z * 2 + lhi;
                const int gr = m0 + row;
                if (gr < NN) {
                    bf16x8 o;
                    if (L0) {
                        const int f0 = l31 * 8;
                        const float* src = (f0 < 128) ? (temb + xt[gr] * 128 + f0)
                                                      : (semb + xs[gr] * 128 + (f0 - 128));
                        f32x4 x0 = *(const f32x4*)src;
                        f32x4 x1 = *(const f32x4*)(src + 4);
                        o[0] = (bf16)x0[0]; o[1] = (bf16)x0[1];
                        o[2] = (bf16)x0[2]; o[3] = (bf16)x0[3];
                        o[4] = (bf16)x1[0]; o[5] = (bf16)x1[1];
                        o[6] = (bf16)x1[2]; o[7] = (bf16)x1[3];
                    } else {
                        o = *(const bf16x8*)(hin + ((size_t)gr << 8) + l31 * 8);
                    }
                    const int unit = row * 32 + (l31 ^ (row & 7));
                    *(bf16x8*)&As[unit * 8] = o;
                }
            }
        } else {
            // ---- aggregation for rows [m0+rbase, +8) ----
            const int gr0 = m0 + rbase;
            if (gr0 < NN) {
                const int rend = (gr0 + 8 < NN) ? (gr0 + 8) : NN;
                int st = offs[seg * NN + gr0];
                const int en = offs[seg * NN + rend];

                float a0 = 0.f, a1 = 0.f, a2 = 0.f, a3 = 0.f;
                int cur = -1;   // wave-uniform block-local row

                while (st < en) {
                    const int cnt = (en - st < 64) ? (en - st) : 64;
                    const int idx = st + ((lane < cnt) ? lane : (cnt - 1));
                    const int pv = epack[idx];                 // tgt meta
                    const int rv = L0 ? epack2[idx]            // etab row
                                      : (pv & SMASK);          // h row
                    int base = 0;

                    // exact-size burst: B unconditional loads + B unconditional consumes
                    auto do_burst = [&](auto bc) {
                        constexpr int B = decltype(bc)::B;
                        bf16x4 hb[B];
#pragma unroll
                        for (int p = 0; p < B; ++p) {
                            const int s = __builtin_amdgcn_readlane(rv, base + p);
                            hb[p] = *(const bf16x4*)(hin + ((size_t)s << 8) + lane * 4);
                        }
#pragma unroll
                        for (int p = 0; p < B; ++p) {
                            const int t = (__builtin_amdgcn_readlane(pv, base + p) >> 20) & 63;
                            if (t != cur) {
                                if (cur >= 0) {
                                    const float inv = readlane_f(ivreg, cur - rbase);
                                    bf16x4 o;
                                    o.x = (bf16)(a0 * inv); o.y = (bf16)(a1 * inv);
                                    o.z = (bf16)(a2 * inv); o.w = (bf16)(a3 * inv);
                                    const int unit = cur * 32 + ((lane >> 1) ^ (cur & 7));
                                    *(bf16x4*)&As[unit * 8 + (lane & 1) * 4] = o;
                                }
                                cur = t; a0 = a1 = a2 = a3 = 0.f;
                            }
                            a0 += (float)hb[p].x; a1 += (float)hb[p].y;
                            a2 += (float)hb[p].z; a3 += (float)hb[p].w;
                        }
                        base += B;
                    };

                    while (cnt - base >= 16) do_burst(ICT<16>{});
                    if (cnt - base >= 8)     do_burst(ICT<8>{});
                    if (cnt - base >= 4)     do_burst(ICT<4>{});
                    if (cnt - base >= 2)     do_burst(ICT<2>{});
                    if (cnt - base >= 1)     do_burst(ICT<1>{});

                    st += cnt;
                }
                if (cur >= 0) {
                    const float inv = readlane_f(ivreg, cur - rbase);
                    bf16x4 o;
                    o.x = (bf16)(a0 * inv); o.y = (bf16)(a1 * inv);
                    o.z = (bf16)(a2 * inv); o.w = (bf16)(a3 * inv);
                    const int unit = cur * 32 + ((lane >> 1) ^ (cur & 7));
                    *(bf16x4*)&As[unit * 8 + (lane & 1) * 4] = o;
                }
            }
        }

        __syncthreads();   // As ready for all waves

        // ---- MFMA: 16 k-steps of 16; B frag = one contiguous 1KB read per step ----
        const bf16* const wseg = Wfrag + ((size_t)(((w >> 1) * 7 + seg) * 16) * 2 * 64) * 8;
#pragma unroll
        for (int step = 0; step < 16; ++step) {
            bf16x8 b0 = *(const bf16x8*)(wseg + ((size_t)(step * 2 + (w & 1)) * 64 + lane) * 8);
            const int ku = step * 2 + lhi;
            bf16x8 a0 = *(const bf16x8*)&As[(l31 * 32 + (ku ^ (l31 & 7))) * 8];
            bf16x8 a1 = *(const bf16x8*)&As[((32 + l31) * 32 + (ku ^ (l31 & 7))) * 8];
            acc[0] = __builtin_amdgcn_mfma_f32_32x32x16_bf16(a0, b0, acc[0], 0, 0, 0);
            acc[1] = __builtin_amdgcn_mfma_f32_32x32x16_bf16(a1, b0, acc[1], 0, 0, 0);
        }
    }

    // ---- epilogue ----
    const float bcol = bias[wc + l31];

    if constexpr (POOL) {
        // fused mean-pool into XCD-sharded buffer (blockIdx&7)
        float* pshard = pooled + (size_t)(blockIdx.x & (NSHARD - 1)) * NGR * HIDD;
        __syncthreads();
        int* bidArr = (int*)As;
        if (tid < 64) {
            const int r = m0 + tid;
            bidArr[tid] = (r < NN) ? batch_ids[r] : -1;
        }
        __syncthreads();
        const int last = (m0 + 63 < NN) ? 63 : (NN - 1 - m0);
        const int glo = bidArr[0];
        const int ghi = bidArr[last];
        for (int g = glo; g <= ghi; ++g) {
            float s0 = 0.f;
#pragma unroll
            for (int rt = 0; rt < 2; ++rt) {
#pragma unroll
                for (int reg = 0; reg < 16; ++reg) {
                    const int rl = rt * 32 + (reg & 3) + 8 * (reg >> 2) + 4 * lhi;
                    if (bidArr[rl] == g)
                        s0 += fmaxf(acc[rt][reg] + bcol, 0.0f);
                }
            }
            s0 += __shfl_xor(s0, 32);
            if (lhi == 0)
                atomicAdd(&pshard[g * HIDD + wc + l31], s0);
        }
    } else {
#pragma unroll
        for (int rt = 0; rt < 2; ++rt) {
#pragma unroll
            for (int reg = 0; reg < 16; ++reg) {
                const int row = m0 + rt * 32 + (reg & 3) + 8 * (reg >> 2) + 4 * lhi;
                if (row < NN) {
                    const int col = wc + l31;
                    float v = acc[rt][reg] + bcol;
                    hout[((size_t)row << 8) + col] = (bf16)fmaxf(v, 0.0f);
                }
            }
        }
    }
}

// ---------------- MLP head (sums pooled shards) ----------------
__global__ __launch_bounds__(256)
void mlp_kernel(const float* __restrict__ pooled, const float* __restrict__ cnt,
                const float* __restrict__ pW1, const float* __restrict__ pb1,
                const float* __restrict__ pW2, const float* __restrict__ pb2,
                float* __restrict__ out)
{
    const int g = blockIdx.x;
    const int d = threadIdx.x;
    __shared__ float pn[HIDD];
    __shared__ float mid[HIDD];
    float c = fmaxf(cnt[g], 1.0f);
    float sacc = 0.f;
#pragma unroll
    for (int x = 0; x < NSHARD; ++x)
        sacc += pooled[(size_t)x * NGR * HIDD + g * HIDD + d];
    pn[d] = sacc / c;
    __syncthreads();
    float s = pb1[d];
    for (int k = 0; k < HIDD; ++k) s = fmaf(pn[k], pW1[k * HIDD + d], s);
    mid[d] = fmaxf(s, 0.0f);
    __syncthreads();
    float s2 = pb2[d];
    for (int k = 0; k < HIDD; ++k) s2 = fmaf(mid[k], pW2[k * HIDD + d], s2);
    out[g * HIDD + d] = s2;
}

extern "C" void kernel_launch(void* const* d_in, const int* in_sizes, int n_in,
                              void* d_out, int out_size, void* d_ws, size_t ws_size,
                              hipStream_t stream)
{
    const int*   x_type    = (const int*)d_in[0];
    const int*   x_sub     = (const int*)d_in[1];
    const int*   edges     = (const int*)d_in[2];
    const int*   batch_ids = (const int*)d_in[3];
    const float* type_emb  = (const float*)d_in[5];
    const float* sub_emb   = (const float*)d_in[6];
    const float* W_rel0    = (const float*)d_in[7];
    const float* W_self0   = (const float*)d_in[8];
    const float* b0        = (const float*)d_in[9];
    const float* W_rel1    = (const float*)d_in[10];
    const float* W_self1   = (const float*)d_in[11];
    const float* b1        = (const float*)d_in[12];
    const float* pW1       = (const float*)d_in[13];
    const float* pb1       = (const float*)d_in[14];
    const float* pW2       = (const float*)d_in[15];
    const float* pb2       = (const float*)d_in[16];
    float* out = (float*)d_out;

    // workspace carve-up (~65 MB)
    char* p = (char*)d_ws;
    auto carve = [&](size_t bytes) { char* q = p; p += (bytes + 255) & ~255ull; return q; };
    bf16*  h1     = (bf16*) carve((size_t)NN * HIDD * sizeof(bf16));     // layer-0 out
    bf16*  Wf0    = (bf16*) carve((size_t)WFRAG_ELEMS * sizeof(bf16));
    bf16*  Wf1    = (bf16*) carve((size_t)WFRAG_ELEMS * sizeof(bf16));
    bf16*  etab   = (bf16*) carve((size_t)1024 * 256 * sizeof(bf16));    // 512 KB
    float* invdeg = (float*)carve((size_t)NN * sizeof(float));
    int*   hist   = (int*)  carve((size_t)NKEY * sizeof(int));
    int*   offs   = (int*)  carve((size_t)(NKEY + 1) * sizeof(int));
    int*   cursor = (int*)  carve((size_t)NKEY * sizeof(int));
    int*   bsum   = (int*)  carve(2048 * sizeof(int));
    int*   epack  = (int*)  carve((size_t)NEDGT * sizeof(int));
    int*   epack2 = (int*)  carve((size_t)NEDGT * sizeof(int));
    float* pooled = (float*)carve((size_t)NSHARD * NGR * HIDD * sizeof(float));  // 1 MB
    float* cnt    = (float*)carve((size_t)NGR * sizeof(float));          // adjacent

    hipMemsetAsync(hist, 0, (size_t)NKEY * sizeof(int), stream);
    hipMemsetAsync(pooled, 0, (size_t)(NSHARD * NGR * HIDD + NGR) * sizeof(float), stream);

    const int NB0 = (NKEY + 2047) / 2048;  // 293
    hist_kernel<<<(NEDGT + 255) / 256, 256, 0, stream>>>(edges, hist);
    scan_l0<<<NB0, 256, 0, stream>>>(hist, offs, bsum, NKEY);
    scan_l1<<<1, 256, 0, stream>>>(bsum, NB0);
    scan_l2<<<(NKEY + 255) / 256, 256, 0, stream>>>(offs, cursor, bsum, hist, invdeg,
                                                    batch_ids, cnt, NKEY);
    scatter_kernel<<<(NEDGT + 255) / 256, 256, 0, stream>>>(edges, cursor, x_type, x_sub,
                                                            epack, epack2);
    build_etab<<<1024, 256, 0, stream>>>(type_emb, sub_emb, etab);

    dim3 wgrid(7, 16, 2);
    build_wfrag<<<wgrid, 256, 0, stream>>>(W_rel0, W_self0, W_rel1, W_self1, Wf0, Wf1);

    const int FGRID = (NN + 63) / 64;   // 1563
    rgcn_fused<true, false><<<FGRID, 512, 0, stream>>>(
        etab, x_type, x_sub, type_emb, sub_emb,
        Wf0, b0, invdeg, offs, epack, epack2, batch_ids, pooled, h1);
    rgcn_fused<false, true><<<FGRID, 512, 0, stream>>>(
        h1, x_type, x_sub, type_emb, sub_emb,
        Wf1, b1, invdeg, offs, epack, epack2, batch_ids, pooled, nullptr);

    mlp_kernel<<<NGR, 256, 0, stream>>>(pooled, cnt, pW1, pb1, pW2, pb2, out);
}